// Round 6
// baseline (187.738 us; speedup 1.0000x reference)
//
#include <hip/hip_runtime.h>

// ---- vector types (ext_vector for [] indexing; avoid HIP name collisions) ----
typedef __attribute__((ext_vector_type(8))) short short8v;      // 8 bf16 (4 VGPR) MFMA frag
typedef __attribute__((ext_vector_type(4))) float floatx4;      // MFMA accum
typedef __attribute__((ext_vector_type(4))) unsigned short ushortx4;

// RNE f32->bf16, 3 VALU ops (values are finite; no NaN path needed)
__device__ __forceinline__ unsigned short f2bf(float f){
  unsigned int u = __float_as_uint(f);
  u += 0x7fffu + ((u >> 16) & 1u);
  return (unsigned short)(u >> 16);
}

__device__ __forceinline__ void gload_lds16(const void* g, void* l){
  __builtin_amdgcn_global_load_lds((const __attribute__((address_space(1))) void*)g,
                                   (__attribute__((address_space(3))) void*)l, 16, 0, 0);
}

// ---- f32 -> bf16 convert, vectorized (G13) ----
__global__ __launch_bounds__(256) void cvt4(const floatx4* __restrict__ s,
                                            ushortx4* __restrict__ d, int n4){
  int i = blockIdx.x * 256 + threadIdx.x;
  if(i < n4){
    floatx4 v = s[i];
    ushortx4 o;
    #pragma unroll
    for(int j = 0; j < 4; ++j) o[j] = f2bf(v[j]);
    d[i] = o;
  }
}

// ---- 2D RoPE cos/sin table: cs[p*64+d] = (cos theta, sin theta) ----
__global__ __launch_bounds__(256) void cs_init(float2* __restrict__ cs){
  int i = blockIdx.x * 256 + threadIdx.x;     // 0..65535
  int p = i >> 6, d = i & 63;
  int y = p >> 5, x = p & 31;
  int dd = d & 31;
  float ifr = powf(10000.0f, -(float)dd * (1.0f / 32.0f));
  float th = (float)(d < 32 ? y : x) * ifr;
  cs[i].x = cosf(th);
  cs[i].y = sinf(th);
}

// ---- GEMM C = A * B^T  (A: M x K bf16 row-major, B: N x K bf16 row-major) ----
// 128x128 tile, BK=32, 4 waves each 64x64 (4x4 frags of 16x16x32 bf16 MFMA).
// v2: 2-phase double-buffered LDS (T3-minimum: stage next BEFORE compute cur,
// one barrier per K-step) + chunk-XOR LDS swizzle (T2/G4, 8-way -> 4-way;
// rule #21: inverse-swizzled global source + swizzled ds_read, linear dest).
// EPI=0: write f32 C.  EPI=1: QKV epilogue (RoPE on q/k, q*=0.125*log2e, V^T).
template<int EPI>
__global__ __launch_bounds__(256) void gemm_bt(
    const unsigned short* __restrict__ A,
    const unsigned short* __restrict__ B,
    int K, int N,
    float* __restrict__ Cf,
    const float2* __restrict__ cs,
    unsigned short* __restrict__ qw,
    unsigned short* __restrict__ kw,
    unsigned short* __restrict__ vtw)
{
  __shared__ unsigned short Al[2][128 * 32];
  __shared__ unsigned short Bl[2][128 * 32];
  const int tid = threadIdx.x;
  const int w = tid >> 6, lane = tid & 63;
  const int g = lane >> 4, c0 = lane & 15;
  const int wr = w >> 1, wc = w & 1;
  const int sw = c0 & 3;                      // read-side swizzle key (row&3 = c0&3)
  const size_t m0 = (size_t)blockIdx.y * 128;
  const size_t n0 = (size_t)blockIdx.x * 128;

  floatx4 acc[4][4] = {};

  // stage tile at k-offset k0s into buffer buf. chunk ci covers (row=ci>>2,
  // chunk=ci&3); LDS linear [row][chunk]; global source chunk = chunk^(row&3).
  auto stage = [&](int k0s, int buf){
    #pragma unroll
    for(int q = 0; q < 2; ++q){
      int ci = q * 256 + tid;
      int row = ci >> 2;
      int ko = ((ci & 3) ^ (row & 3)) << 3;
      gload_lds16(A + (m0 + row) * K + k0s + ko, &Al[buf][(size_t)(q * 256 + w * 64) * 8]);
      gload_lds16(B + (n0 + row) * K + k0s + ko, &Bl[buf][(size_t)(q * 256 + w * 64) * 8]);
    }
  };
  auto compute = [&](int buf){
    short8v am[4], bn[4];
    #pragma unroll
    for(int mf = 0; mf < 4; ++mf)
      am[mf] = *(const short8v*)&Al[buf][(wr * 64 + mf * 16 + c0) * 32 + ((g ^ sw) << 3)];
    #pragma unroll
    for(int nf = 0; nf < 4; ++nf)
      bn[nf] = *(const short8v*)&Bl[buf][(wc * 64 + nf * 16 + c0) * 32 + ((g ^ sw) << 3)];
    #pragma unroll
    for(int mf = 0; mf < 4; ++mf)
      #pragma unroll
      for(int nf = 0; nf < 4; ++nf)
        acc[mf][nf] = __builtin_amdgcn_mfma_f32_16x16x32_bf16(am[mf], bn[nf], acc[mf][nf], 0, 0, 0);
  };

  // prologue: stage tile 0 into buf 0
  stage(0, 0);
  __syncthreads();
  // K multiple of 64: manual unroll-by-2 keeps buffer index compile-time (rule #20)
  for(int k0 = 0; k0 < K; k0 += 64){
    if(k0 + 32 < K) stage(k0 + 32, 1);
    compute(0);
    __syncthreads();            // alt staged (vmcnt drained) + all done reading buf0
    if(k0 + 64 < K) stage(k0 + 64, 0);
    compute(1);
    __syncthreads();
  }

  // C-layout: col = lane&15 (=c0), row = (lane>>4)*4 + r  [m89-verified]
  if(EPI == 0){
    #pragma unroll
    for(int mf = 0; mf < 4; ++mf){
      size_t mrow = m0 + wr * 64 + mf * 16 + g * 4;
      #pragma unroll
      for(int nf = 0; nf < 4; ++nf){
        size_t n = n0 + wc * 64 + nf * 16 + c0;
        #pragma unroll
        for(int r = 0; r < 4; ++r)
          Cf[(mrow + r) * N + n] = acc[mf][nf][r];
      }
    }
  } else {
    int t = (int)(n0 >> 6) + wc;          // 0..47
    int sect = t % 3, hh = t / 3;         // 0=q,1=k,2=v ; head
    if(sect == 2){
      // V -> V^T [bh][64][1024]; pack 4 consecutive n-positions (regs) per store
      #pragma unroll
      for(int mf = 0; mf < 4; ++mf){
        size_t m = m0 + wr * 64 + mf * 16 + g * 4;
        int b = (int)(m >> 10); int p = (int)(m & 1023);
        #pragma unroll
        for(int nf = 0; nf < 4; ++nf){
          int d = nf * 16 + c0;
          ushortx4 pk;
          #pragma unroll
          for(int r = 0; r < 4; ++r) pk[r] = f2bf(acc[mf][nf][r]);
          *(ushortx4*)(vtw + ((size_t)(b * 16 + hh) * 64 + d) * 1024 + p) = pk;
        }
      }
    } else {
      // RoPE: pairs (d, d+32) live in frags (nf, nf+2) of the same thread
      unsigned short* dst = (sect == 0) ? qw : kw;
      // fold attention scale AND log2(e) (exp2-domain softmax) into Q
      const float qs = (sect == 0) ? 0.18033688011112042f : 1.0f;
      #pragma unroll
      for(int mf = 0; mf < 4; ++mf){
        #pragma unroll
        for(int r = 0; r < 4; ++r){
          size_t m = m0 + wr * 64 + mf * 16 + g * 4 + r;
          int b = (int)(m >> 10); int p = (int)(m & 1023);
          const float2* csr = cs + (size_t)p * 64;
          unsigned short* orow = dst + ((size_t)(b * 16 + hh) * 1024 + p) * 64;
          #pragma unroll
          for(int nf = 0; nf < 2; ++nf){
            int d = nf * 16 + c0;
            float x1 = acc[mf][nf][r], x2 = acc[mf][nf + 2][r];
            float2 cc1 = csr[d], cc2 = csr[d + 32];
            orow[d]      = f2bf((x1 * cc1.x - x2 * cc1.y) * qs);
            orow[d + 32] = f2bf((x2 * cc2.x + x1 * cc2.y) * qs);
          }
        }
      }
    }
  }
}

// ---- flash attention v4b: 512 blocks x 512 thr (8 waves, 32 q-rows each) ----
// K/V tiles staged in LDS (shared by 8 waves), double-buffered, prefetched one
// iteration ahead via global_load_lds (T3 minimum 2-phase). XOR-swizzled K/V
// LDS layout (G4 / rule #21: linear LDS dest + inverse-swizzled global src).
// exp2-domain softmax, defer-max, deferred l-reduce, wave-private P buffer.
__global__ __launch_bounds__(512, 4) void attn_kernel(
    const unsigned short* __restrict__ qw,
    const unsigned short* __restrict__ kw,
    const unsigned short* __restrict__ vtw,
    unsigned short* __restrict__ ow)
{
  // LDS: KV double-buffer 2x16KB (K 8KB + V 8KB each), then P 8x4KB
  __shared__ char smem[65536];
  const int tid = threadIdx.x;
  const int w = tid >> 6, lane = tid & 63;
  const int g = lane >> 4, c0 = lane & 15;
  // XCD-aware decode: all 4 q-tiles of one bh on the same XCD
  const int bb = blockIdx.x;                  // 0..511
  const int xcd = bb & 7, slot = bb >> 3;     // slot 0..63
  const int bh = xcd + ((slot >> 2) << 3);    // 0..127
  const int qt = slot & 3;
  const size_t bhoff = (size_t)bh * 1024 * 64;
  const unsigned short* Qb = qw + bhoff;
  const unsigned short* Kb = kw + bhoff;
  const unsigned short* Vb = vtw + bhoff;
  const int q0 = qt * 256 + w * 32;
  char* Pw = smem + 32768 + w * 4096;

  // staging geometry: chunk = tid (0..511); row = chunk>>3, j = chunk&7
  // LDS holds tile with byte swizzle ((row&7)<<4); gload_lds dest is linear,
  // so the global SOURCE is inverse-permuted: j_src = j ^ (row&7).
  const int srow = tid >> 3;
  const int sjx = ((tid & 7) ^ (srow & 7)) << 3;    // element offset in row
  const unsigned short* ksrc = Kb + srow * 64 + sjx;           // + kvt*4096
  const unsigned short* vsrc = Vb + (size_t)srow * 1024 + sjx; // + kv0
  // wave-uniform LDS dest bases (lane*16 added by HW)
  const int wbase = w * 1024;

  // Q as B-operand, hoisted: [qf][chain]  (col=c0 -> q0+qf*16+c0 ; k=d=g*8+j+32i)
  short8v bq[2][2];
  #pragma unroll
  for(int qf = 0; qf < 2; ++qf)
    #pragma unroll
    for(int i = 0; i < 2; ++i)
      bq[qf][i] = *(const short8v*)(Qb + (size_t)(q0 + qf * 16 + c0) * 64 + g * 8 + i * 32);

  floatx4 o[2][4] = {};                 // [qf(=mf)][nf]; row=q=mf*16+g*4+r, col=d=nf*16+c0
  float m_run[2] = {-1e30f, -1e30f};
  float l_part[2] = {0.0f, 0.0f};       // per-thread partial (xor-reduced at end)

  // prologue: stage tile 0 into buffer 0
  gload_lds16(ksrc, smem + wbase);
  gload_lds16(vsrc, smem + 8192 + wbase);
  __syncthreads();

  int cur = 0;
  for(int kv0 = 0; kv0 < 1024; kv0 += 64){
    char* Ksm = smem + cur * 16384;
    char* Vsm = smem + cur * 16384 + 8192;
    // prefetch next tile into alternate buffer
    // (K tile step = 64 rows x 64 elem = 4096 elements; V^T step = 64 columns)
    if(kv0 + 64 < 1024){
      char* alt = smem + (cur ^ 1) * 16384;
      gload_lds16(ksrc + (size_t)(kv0 + 64) * 64, alt + wbase);
      gload_lds16(vsrc + kv0 + 64, alt + 8192 + wbase);
    }
    // S^T tile (64 kv x 32 q), log2-domain: A = K rows from LDS (swizzled read)
    floatx4 st[4][2];
    #pragma unroll
    for(int kf = 0; kf < 4; ++kf){
      const int krow = kf * 16 + c0;
      const char* kr = Ksm + (krow << 7);
      short8v ka0 = *(const short8v*)(kr + (((g    ) ^ (c0 & 7)) << 4));
      short8v ka1 = *(const short8v*)(kr + (((g + 4) ^ (c0 & 7)) << 4));
      #pragma unroll
      for(int qf = 0; qf < 2; ++qf){
        floatx4 z = {};
        z = __builtin_amdgcn_mfma_f32_16x16x32_bf16(ka0, bq[qf][0], z, 0, 0, 0);
        st[kf][qf] = __builtin_amdgcn_mfma_f32_16x16x32_bf16(ka1, bq[qf][1], z, 0, 0, 0);
      }
    }
    // per-q-column max (thread holds 16 kv values per qf; finish via xor 16,32)
    float vmax[2];
    #pragma unroll
    for(int qf = 0; qf < 2; ++qf){
      float vm = -1e30f;
      #pragma unroll
      for(int kf = 0; kf < 4; ++kf)
        #pragma unroll
        for(int r = 0; r < 4; ++r) vm = fmaxf(vm, st[kf][qf][r]);
      vm = fmaxf(vm, __shfl_xor(vm, 16));
      vm = fmaxf(vm, __shfl_xor(vm, 32));
      vmax[qf] = vm;
    }
    // T13 defer-max: only rescale when max grew by > 8 (values bounded by 2^8)
    if(!__all(vmax[0] <= m_run[0] + 8.0f && vmax[1] <= m_run[1] + 8.0f)){
      #pragma unroll
      for(int qf = 0; qf < 2; ++qf){
        float m_new = fmaxf(m_run[qf], vmax[qf]);
        float sc = __builtin_amdgcn_exp2f(m_run[qf] - m_new);
        l_part[qf] *= sc;
        m_run[qf] = m_new;
        float f0 = __shfl(sc, g * 4 + 0);
        float f1 = __shfl(sc, g * 4 + 1);
        float f2 = __shfl(sc, g * 4 + 2);
        float f3 = __shfl(sc, g * 4 + 3);
        #pragma unroll
        for(int nf = 0; nf < 4; ++nf){
          o[qf][nf][0] *= f0; o[qf][nf][1] *= f1; o[qf][nf][2] *= f2; o[qf][nf][3] *= f3;
        }
      }
    }
    // P = exp2(S - m), bf16 pack; per-thread partial row-sums (reduce at end)
    #pragma unroll
    for(int qf = 0; qf < 2; ++qf){
      float ps = 0.0f;
      #pragma unroll
      for(int kf = 0; kf < 4; ++kf){
        ushortx4 pk;
        #pragma unroll
        for(int r = 0; r < 4; ++r){
          float e = __builtin_amdgcn_exp2f(st[kf][qf][r] - m_run[qf]);
          ps += e;
          pk[r] = f2bf(e);
        }
        // P -> LDS [q=qf*16+c0][kv=kf*16+g*4], XOR-swizzled (G4)
        int byo = (qf << 11) + (c0 << 7) + (kf << 5) + (g << 3);
        byo ^= (c0 & 7) << 4;
        *(ushortx4*)(Pw + byo) = pk;
      }
      l_part[qf] += ps;
    }
    // P as A-operand: row=q=mf*16+c0, k=kv=g*8+j(+32i)  (wave-private: no barrier)
    short8v pa[2][2];
    #pragma unroll
    for(int mf = 0; mf < 2; ++mf)
      #pragma unroll
      for(int i = 0; i < 2; ++i){
        int byo = (mf << 11) + (c0 << 7) + (i << 6) + (g << 4);
        byo ^= (c0 & 7) << 4;
        pa[mf][i] = *(const short8v*)(Pw + byo);
      }
    // V^T as B-operand from LDS: row=d=nf*16+c0, k=kv=g*8+j(+32i), swizzled
    #pragma unroll
    for(int nf = 0; nf < 4; ++nf){
      const int vrow = nf * 16 + c0;
      const char* vr = Vsm + (vrow << 7);
      short8v v0 = *(const short8v*)(vr + (((g    ) ^ (c0 & 7)) << 4));
      short8v v1 = *(const short8v*)(vr + (((g + 4) ^ (c0 & 7)) << 4));
      #pragma unroll
      for(int mf = 0; mf < 2; ++mf){
        o[mf][nf] = __builtin_amdgcn_mfma_f32_16x16x32_bf16(pa[mf][0], v0, o[mf][nf], 0, 0, 0);
        o[mf][nf] = __builtin_amdgcn_mfma_f32_16x16x32_bf16(pa[mf][1], v1, o[mf][nf], 0, 0, 0);
      }
    }
    __syncthreads();     // next tile staged (vmcnt drained) + all waves done with cur
    cur ^= 1;
  }

  const int b = bh >> 4, hh = bh & 15;
  #pragma unroll
  for(int mf = 0; mf < 2; ++mf){
    l_part[mf] += __shfl_xor(l_part[mf], 16);
    l_part[mf] += __shfl_xor(l_part[mf], 32);
    float i0 = 1.0f / __shfl(l_part[mf], g * 4 + 0);
    float i1 = 1.0f / __shfl(l_part[mf], g * 4 + 1);
    float i2 = 1.0f / __shfl(l_part[mf], g * 4 + 2);
    float i3 = 1.0f / __shfl(l_part[mf], g * 4 + 3);
    #pragma unroll
    for(int nf = 0; nf < 4; ++nf){
      o[mf][nf][0] *= i0; o[mf][nf][1] *= i1; o[mf][nf][2] *= i2; o[mf][nf][3] *= i3;
      #pragma unroll
      for(int r = 0; r < 4; ++r){
        size_t row = (size_t)b * 1024 + q0 + mf * 16 + g * 4 + r;
        ow[row * 1024 + hh * 64 + nf * 16 + c0] = f2bf(o[mf][nf][r]);
      }
    }
  }
}

// ---- workspace layout (bytes) ----
//   bfT    @ 0         16,777,216   tensor bf16 (8192x1024)
//   bfWq   @ 16777216   6,291,456   w_qkv bf16 (3072x1024)
//   bfWp   @ 23068672   2,097,152   w_proj bf16 (1024x1024)
//   cs     @ 25165824     524,288   RoPE table float2 (1024x64)
//   qw     @ 25690112  16,777,216   Q rope'd*scale bf16 [bh][1024][64]
//   kw     @ 42467328  16,777,216   K rope'd bf16 [bh][1024][64]
//   vtw    @ 59244544  16,777,216   V^T bf16 [bh][64][1024]
//   ow     @ 76021760  16,777,216   attn out bf16 [b*n][c]

extern "C" void kernel_launch(void* const* d_in, const int* in_sizes, int n_in,
                              void* d_out, int out_size, void* d_ws, size_t ws_size,
                              hipStream_t stream){
  const float* tensor = (const float*)d_in[0];
  const float* w_qkv  = (const float*)d_in[1];
  const float* w_proj = (const float*)d_in[2];
  char* ws = (char*)d_ws;
  unsigned short* bfT  = (unsigned short*)(ws);
  unsigned short* bfWq = (unsigned short*)(ws + 16777216);
  unsigned short* bfWp = (unsigned short*)(ws + 23068672);
  float2*         cs   = (float2*)        (ws + 25165824);
  unsigned short* qw   = (unsigned short*)(ws + 25690112);
  unsigned short* kw   = (unsigned short*)(ws + 42467328);
  unsigned short* vtw  = (unsigned short*)(ws + 59244544);
  unsigned short* owp  = (unsigned short*)(ws + 76021760);

  cvt4<<<8192, 256, 0, stream>>>((const floatx4*)tensor, (ushortx4*)bfT, 2097152);
  cvt4<<<3072, 256, 0, stream>>>((const floatx4*)w_qkv,  (ushortx4*)bfWq, 786432);
  cvt4<<<1024, 256, 0, stream>>>((const floatx4*)w_proj, (ushortx4*)bfWp, 262144);
  cs_init<<<256, 256, 0, stream>>>(cs);

  // QKV: M=8192, N=3072, K=1024 ; fused RoPE epilogue
  gemm_bt<1><<<dim3(24, 64), 256, 0, stream>>>(bfT, bfWq, 1024, 3072,
                                               nullptr, cs, qw, kw, vtw);
  // attention: 512 blocks x 512 threads, XCD-swizzled decode inside the kernel
  attn_kernel<<<512, 512, 0, stream>>>(qw, kw, vtw, owp);
  // proj: M=8192, N=1024, K=1024 ; f32 out
  gemm_bt<0><<<dim3(8, 64), 256, 0, stream>>>(owp, bfWp, 1024, 1024,
                                              (float*)d_out, nullptr, nullptr, nullptr, nullptr);
}

// Round 7
// 175.121 us; speedup vs baseline: 1.0720x; 1.0720x over previous
//
#include <hip/hip_runtime.h>

// ---- vector types (ext_vector for [] indexing; avoid HIP name collisions) ----
typedef __attribute__((ext_vector_type(8))) short short8v;      // 8 bf16 (4 VGPR) MFMA frag
typedef __attribute__((ext_vector_type(4))) float floatx4;      // MFMA accum
typedef __attribute__((ext_vector_type(4))) unsigned short ushortx4;

// RNE f32->bf16, 3 VALU ops (values are finite; no NaN path needed)
__device__ __forceinline__ unsigned short f2bf(float f){
  unsigned int u = __float_as_uint(f);
  u += 0x7fffu + ((u >> 16) & 1u);
  return (unsigned short)(u >> 16);
}

__device__ __forceinline__ void gload_lds16(const void* g, void* l){
  __builtin_amdgcn_global_load_lds((const __attribute__((address_space(1))) void*)g,
                                   (__attribute__((address_space(3))) void*)l, 16, 0, 0);
}

// ---- f32 -> bf16 convert, vectorized (G13) ----
__global__ __launch_bounds__(256) void cvt4(const floatx4* __restrict__ s,
                                            ushortx4* __restrict__ d, int n4){
  int i = blockIdx.x * 256 + threadIdx.x;
  if(i < n4){
    floatx4 v = s[i];
    ushortx4 o;
    #pragma unroll
    for(int j = 0; j < 4; ++j) o[j] = f2bf(v[j]);
    d[i] = o;
  }
}

// ---- 2D RoPE cos/sin table: cs[p*64+d] = (cos theta, sin theta) ----
__global__ __launch_bounds__(256) void cs_init(float2* __restrict__ cs){
  int i = blockIdx.x * 256 + threadIdx.x;     // 0..65535
  int p = i >> 6, d = i & 63;
  int y = p >> 5, x = p & 31;
  int dd = d & 31;
  float ifr = powf(10000.0f, -(float)dd * (1.0f / 32.0f));
  float th = (float)(d < 32 ? y : x) * ifr;
  cs[i].x = cosf(th);
  cs[i].y = sinf(th);
}

// ---- 8-phase 256x256 GEMM  C = A * B^T  (A: [M][K], B: [N][K], bf16) ----
// m201-style template: BK=64 (two K-halves of 32), 8 waves (2M x 4N), 512 thr,
// 128KB LDS (A,B x dbuf x kh). Raw s_barrier (NO implicit vmcnt drain) +
// counted vmcnt(4) once per K-tile keeps stages in flight across barriers.
// Stage slots: tile t ph1: A,B(t+1)kh1 ; ph3: A(t+2)kh0 ; ph4: B(t+2)kh0.
// LDS chunk swizzle: chunk = g ^ ((row>>1)&3), inverse-applied on global src.
// EPI=0: f32 C. EPI=1: QKV epilogue (RoPE q/k, q*=0.125*log2e, V transposed).
template<int EPI>
__global__ __launch_bounds__(512, 2) void gemm8(
    const unsigned short* __restrict__ A,
    const unsigned short* __restrict__ B,
    int K, int N, int NXB,
    float* __restrict__ Cf,
    const float2* __restrict__ cs,
    unsigned short* __restrict__ qw,
    unsigned short* __restrict__ kw,
    unsigned short* __restrict__ vtw)
{
  __shared__ char lds[131072];          // A: 0..64K, B: 64K..128K
  const int tid = threadIdx.x;
  const int w = tid >> 6, lane = tid & 63;
  const int g = lane >> 4, c0 = lane & 15;
  const int wm = w >> 2, wn = w & 3;    // 2 x 4 wave grid; wave tile 128x64
  const int NT = K >> 6;                // K-tiles of 64

  // XCD-bijective block decode (nwg % 8 == 0): each XCD gets a contiguous chunk
  const int per = gridDim.x >> 3;
  const int wg = (blockIdx.x & 7) * per + (blockIdx.x >> 3);
  const int by = wg / NXB, bx = wg % NXB;
  const size_t m0 = (size_t)by * 256;
  const size_t n0 = (size_t)bx * 256;

  // staging: ci = q*512+tid covers (row=ci>>2, chunk=ci&3) of a [256][32] half.
  // LDS dest linear; global src chunk = (ci&3) ^ ((row>>1)&3)  [involution]
  const int row0 = tid >> 2;                       // q=0 row; q=1: +128
  const int xch = (tid & 3) ^ ((tid >> 3) & 3);    // q-invariant
  const unsigned short* sA0 = A + (m0 + row0) * K + xch * 8;
  const unsigned short* sA1 = A + (m0 + row0 + 128) * K + xch * 8;
  const unsigned short* sB0 = B + (n0 + row0) * K + xch * 8;
  const unsigned short* sB1 = B + (n0 + row0 + 128) * K + xch * 8;
  char* const Ald = lds;
  char* const Bld = lds + 65536;
  const int wb = w * 1024;              // wave-uniform LDS dest base (lane*16 by HW)

  auto stA = [&](int t, int buf, int kh){
    char* d = Ald + buf * 32768 + kh * 16384 + wb;
    gload_lds16(sA0 + t * 64 + kh * 32, d);
    gload_lds16(sA1 + t * 64 + kh * 32, d + 8192);
  };
  auto stB = [&](int t, int buf, int kh){
    char* d = Bld + buf * 32768 + kh * 16384 + wb;
    gload_lds16(sB0 + t * 64 + kh * 32, d);
    gload_lds16(sB1 + t * 64 + kh * 32, d + 8192);
  };

  // swizzled read: chunk = g ^ ((row>>1)&3); row&3 = c0&3 for all frag rows
  const int archy = (g ^ ((c0 >> 1) & 3)) << 4;
  auto rdA = [&](int buf, int kh, int mf) -> short8v {
    return *(const short8v*)(Ald + buf * 32768 + kh * 16384 +
                             (wm * 128 + mf * 16 + c0) * 64 + archy);
  };
  auto rdB = [&](int buf, int kh, int nf) -> short8v {
    return *(const short8v*)(Bld + buf * 32768 + kh * 16384 +
                             (wn * 64 + nf * 16 + c0) * 64 + archy);
  };

  floatx4 acc[8][4] = {};

#define BARX() do{ __builtin_amdgcn_s_barrier(); __builtin_amdgcn_sched_barrier(0); }while(0)

  auto tile4 = [&](int t, int buf){
    const int ob = buf ^ 1;
    const int tn1 = (t + 1 < NT) ? t + 1 : NT - 1;
    const int tn2 = (t + 2 < NT) ? t + 2 : NT - 1;
    short8v am[4], bn[4];
    // ph1: kh0 B-all + A mf0-3 ; stage A,B(t+1) kh1 -> other buf
    #pragma unroll
    for(int nf = 0; nf < 4; ++nf) bn[nf] = rdB(buf, 0, nf);
    #pragma unroll
    for(int mf = 0; mf < 4; ++mf) am[mf] = rdA(buf, 0, mf);
    stA(tn1, ob, 1); stB(tn1, ob, 1);
    BARX();
    __builtin_amdgcn_s_setprio(1);
    #pragma unroll
    for(int mf = 0; mf < 4; ++mf)
      #pragma unroll
      for(int nf = 0; nf < 4; ++nf)
        acc[mf][nf] = __builtin_amdgcn_mfma_f32_16x16x32_bf16(am[mf], bn[nf], acc[mf][nf], 0, 0, 0);
    __builtin_amdgcn_s_setprio(0);
    BARX();
    // ph2: kh0 A mf4-7 (B kh0 held in regs)
    #pragma unroll
    for(int mf = 0; mf < 4; ++mf) am[mf] = rdA(buf, 0, 4 + mf);
    BARX();
    __builtin_amdgcn_s_setprio(1);
    #pragma unroll
    for(int mf = 0; mf < 4; ++mf)
      #pragma unroll
      for(int nf = 0; nf < 4; ++nf)
        acc[4 + mf][nf] = __builtin_amdgcn_mfma_f32_16x16x32_bf16(am[mf], bn[nf], acc[4 + mf][nf], 0, 0, 0);
    __builtin_amdgcn_s_setprio(0);
    BARX();
    // ph3: kh1 B-all + A mf0-3 ; stage A(t+2) kh0 -> this buf (kh0 reads done ph2)
    #pragma unroll
    for(int nf = 0; nf < 4; ++nf) bn[nf] = rdB(buf, 1, nf);
    #pragma unroll
    for(int mf = 0; mf < 4; ++mf) am[mf] = rdA(buf, 1, mf);
    stA(tn2, buf, 0);
    BARX();
    __builtin_amdgcn_s_setprio(1);
    #pragma unroll
    for(int mf = 0; mf < 4; ++mf)
      #pragma unroll
      for(int nf = 0; nf < 4; ++nf)
        acc[mf][nf] = __builtin_amdgcn_mfma_f32_16x16x32_bf16(am[mf], bn[nf], acc[mf][nf], 0, 0, 0);
    __builtin_amdgcn_s_setprio(0);
    BARX();
    // ph4: kh1 A mf4-7 ; stage B(t+2) kh0 ; counted vmcnt (T4) then barrier
    #pragma unroll
    for(int mf = 0; mf < 4; ++mf) am[mf] = rdA(buf, 1, 4 + mf);
    stB(tn2, buf, 0);
    BARX();
    __builtin_amdgcn_s_setprio(1);
    #pragma unroll
    for(int mf = 0; mf < 4; ++mf)
      #pragma unroll
      for(int nf = 0; nf < 4; ++nf)
        acc[4 + mf][nf] = __builtin_amdgcn_mfma_f32_16x16x32_bf16(am[mf], bn[nf], acc[4 + mf][nf], 0, 0, 0);
    __builtin_amdgcn_s_setprio(0);
    // allow 4 loads (ph3+ph4 stages) outstanding; everything older retired:
    // next tile's kh0 (staged 2 tiles ago) and kh1 (this ph1) are now in LDS.
    asm volatile("s_waitcnt vmcnt(4)" ::: "memory");
    BARX();
  };

  // prologue: tile0 full + tile1 kh0; wait tile0 (leave tile1-kh0 flying)
  stA(0, 0, 0); stB(0, 0, 0);
  stA(0, 0, 1); stB(0, 0, 1);
  stA(1, 1, 0); stB(1, 1, 0);
  asm volatile("s_waitcnt vmcnt(4)" ::: "memory");
  BARX();

  for(int t = 0; t < NT; t += 2){ tile4(t, 0); tile4(t + 1, 1); }
  __syncthreads();    // full drain: no dangling gload_lds writes past kernel end
#undef BARX

  // ---- epilogue ---- C-layout: col = c0, row = g*4 + r  [m89-verified]
  if(EPI == 0){
    #pragma unroll
    for(int mf = 0; mf < 8; ++mf){
      size_t mrow = m0 + wm * 128 + mf * 16 + g * 4;
      #pragma unroll
      for(int nf = 0; nf < 4; ++nf){
        size_t n = n0 + wn * 64 + nf * 16 + c0;
        #pragma unroll
        for(int r = 0; r < 4; ++r)
          Cf[(mrow + r) * N + n] = acc[mf][nf][r];
      }
    }
  } else {
    int t = (int)(n0 >> 6) + wn;          // 64-col group: 0..47
    int sect = t % 3, hh = t / 3;         // 0=q,1=k,2=v ; head
    if(sect == 2){
      // V -> V^T [bh][64][1024]
      #pragma unroll
      for(int mf = 0; mf < 8; ++mf){
        size_t m = m0 + wm * 128 + mf * 16 + g * 4;
        int b = (int)(m >> 10); int p = (int)(m & 1023);
        #pragma unroll
        for(int nf = 0; nf < 4; ++nf){
          int d = nf * 16 + c0;
          ushortx4 pk;
          #pragma unroll
          for(int r = 0; r < 4; ++r) pk[r] = f2bf(acc[mf][nf][r]);
          *(ushortx4*)(vtw + ((size_t)(b * 16 + hh) * 64 + d) * 1024 + p) = pk;
        }
      }
    } else {
      // RoPE: pairs (d, d+32) live in frags (nf, nf+2) of the same thread
      unsigned short* dst = (sect == 0) ? qw : kw;
      const float qs = (sect == 0) ? 0.18033688011112042f : 1.0f;  // 0.125*log2e
      #pragma unroll
      for(int mf = 0; mf < 8; ++mf){
        #pragma unroll
        for(int r = 0; r < 4; ++r){
          size_t m = m0 + wm * 128 + mf * 16 + g * 4 + r;
          int b = (int)(m >> 10); int p = (int)(m & 1023);
          const float2* csr = cs + (size_t)p * 64;
          unsigned short* orow = dst + ((size_t)(b * 16 + hh) * 1024 + p) * 64;
          #pragma unroll
          for(int nf = 0; nf < 2; ++nf){
            int d = nf * 16 + c0;
            float x1 = acc[mf][nf][r], x2 = acc[mf][nf + 2][r];
            float2 cc1 = csr[d], cc2 = csr[d + 32];
            orow[d]      = f2bf((x1 * cc1.x - x2 * cc1.y) * qs);
            orow[d + 32] = f2bf((x2 * cc2.x + x1 * cc2.y) * qs);
          }
        }
      }
    }
  }
}

// ---- flash attention v4b: 512 blocks x 512 thr (8 waves, 32 q-rows each) ----
// K/V tiles staged in LDS (shared by 8 waves), double-buffered, prefetched one
// iteration ahead via global_load_lds. XOR-swizzled K/V LDS layout.
// exp2-domain softmax, defer-max, deferred l-reduce, wave-private P buffer.
__global__ __launch_bounds__(512, 4) void attn_kernel(
    const unsigned short* __restrict__ qw,
    const unsigned short* __restrict__ kw,
    const unsigned short* __restrict__ vtw,
    unsigned short* __restrict__ ow)
{
  __shared__ char smem[65536];
  const int tid = threadIdx.x;
  const int w = tid >> 6, lane = tid & 63;
  const int g = lane >> 4, c0 = lane & 15;
  const int bb = blockIdx.x;                  // 0..511
  const int xcd = bb & 7, slot = bb >> 3;
  const int bh = xcd + ((slot >> 2) << 3);
  const int qt = slot & 3;
  const size_t bhoff = (size_t)bh * 1024 * 64;
  const unsigned short* Qb = qw + bhoff;
  const unsigned short* Kb = kw + bhoff;
  const unsigned short* Vb = vtw + bhoff;
  const int q0 = qt * 256 + w * 32;
  char* Pw = smem + 32768 + w * 4096;

  const int srow = tid >> 3;
  const int sjx = ((tid & 7) ^ (srow & 7)) << 3;
  const unsigned short* ksrc = Kb + srow * 64 + sjx;
  const unsigned short* vsrc = Vb + (size_t)srow * 1024 + sjx;
  const int wbase = w * 1024;

  short8v bq[2][2];
  #pragma unroll
  for(int qf = 0; qf < 2; ++qf)
    #pragma unroll
    for(int i = 0; i < 2; ++i)
      bq[qf][i] = *(const short8v*)(Qb + (size_t)(q0 + qf * 16 + c0) * 64 + g * 8 + i * 32);

  floatx4 o[2][4] = {};
  float m_run[2] = {-1e30f, -1e30f};
  float l_part[2] = {0.0f, 0.0f};

  gload_lds16(ksrc, smem + wbase);
  gload_lds16(vsrc, smem + 8192 + wbase);
  __syncthreads();

  int cur = 0;
  for(int kv0 = 0; kv0 < 1024; kv0 += 64){
    char* Ksm = smem + cur * 16384;
    char* Vsm = smem + cur * 16384 + 8192;
    if(kv0 + 64 < 1024){
      char* alt = smem + (cur ^ 1) * 16384;
      gload_lds16(ksrc + (size_t)(kv0 + 64) * 64, alt + wbase);
      gload_lds16(vsrc + kv0 + 64, alt + 8192 + wbase);
    }
    floatx4 st[4][2];
    #pragma unroll
    for(int kf = 0; kf < 4; ++kf){
      const int krow = kf * 16 + c0;
      const char* kr = Ksm + (krow << 7);
      short8v ka0 = *(const short8v*)(kr + (((g    ) ^ (c0 & 7)) << 4));
      short8v ka1 = *(const short8v*)(kr + (((g + 4) ^ (c0 & 7)) << 4));
      #pragma unroll
      for(int qf = 0; qf < 2; ++qf){
        floatx4 z = {};
        z = __builtin_amdgcn_mfma_f32_16x16x32_bf16(ka0, bq[qf][0], z, 0, 0, 0);
        st[kf][qf] = __builtin_amdgcn_mfma_f32_16x16x32_bf16(ka1, bq[qf][1], z, 0, 0, 0);
      }
    }
    float vmax[2];
    #pragma unroll
    for(int qf = 0; qf < 2; ++qf){
      float vm = -1e30f;
      #pragma unroll
      for(int kf = 0; kf < 4; ++kf)
        #pragma unroll
        for(int r = 0; r < 4; ++r) vm = fmaxf(vm, st[kf][qf][r]);
      vm = fmaxf(vm, __shfl_xor(vm, 16));
      vm = fmaxf(vm, __shfl_xor(vm, 32));
      vmax[qf] = vm;
    }
    if(!__all(vmax[0] <= m_run[0] + 8.0f && vmax[1] <= m_run[1] + 8.0f)){
      #pragma unroll
      for(int qf = 0; qf < 2; ++qf){
        float m_new = fmaxf(m_run[qf], vmax[qf]);
        float sc = __builtin_amdgcn_exp2f(m_run[qf] - m_new);
        l_part[qf] *= sc;
        m_run[qf] = m_new;
        float f0 = __shfl(sc, g * 4 + 0);
        float f1 = __shfl(sc, g * 4 + 1);
        float f2 = __shfl(sc, g * 4 + 2);
        float f3 = __shfl(sc, g * 4 + 3);
        #pragma unroll
        for(int nf = 0; nf < 4; ++nf){
          o[qf][nf][0] *= f0; o[qf][nf][1] *= f1; o[qf][nf][2] *= f2; o[qf][nf][3] *= f3;
        }
      }
    }
    #pragma unroll
    for(int qf = 0; qf < 2; ++qf){
      float ps = 0.0f;
      #pragma unroll
      for(int kf = 0; kf < 4; ++kf){
        ushortx4 pk;
        #pragma unroll
        for(int r = 0; r < 4; ++r){
          float e = __builtin_amdgcn_exp2f(st[kf][qf][r] - m_run[qf]);
          ps += e;
          pk[r] = f2bf(e);
        }
        int byo = (qf << 11) + (c0 << 7) + (kf << 5) + (g << 3);
        byo ^= (c0 & 7) << 4;
        *(ushortx4*)(Pw + byo) = pk;
      }
      l_part[qf] += ps;
    }
    short8v pa[2][2];
    #pragma unroll
    for(int mf = 0; mf < 2; ++mf)
      #pragma unroll
      for(int i = 0; i < 2; ++i){
        int byo = (mf << 11) + (c0 << 7) + (i << 6) + (g << 4);
        byo ^= (c0 & 7) << 4;
        pa[mf][i] = *(const short8v*)(Pw + byo);
      }
    #pragma unroll
    for(int nf = 0; nf < 4; ++nf){
      const int vrow = nf * 16 + c0;
      const char* vr = Vsm + (vrow << 7);
      short8v v0 = *(const short8v*)(vr + (((g    ) ^ (c0 & 7)) << 4));
      short8v v1 = *(const short8v*)(vr + (((g + 4) ^ (c0 & 7)) << 4));
      #pragma unroll
      for(int mf = 0; mf < 2; ++mf){
        o[mf][nf] = __builtin_amdgcn_mfma_f32_16x16x32_bf16(pa[mf][0], v0, o[mf][nf], 0, 0, 0);
        o[mf][nf] = __builtin_amdgcn_mfma_f32_16x16x32_bf16(pa[mf][1], v1, o[mf][nf], 0, 0, 0);
      }
    }
    __syncthreads();
    cur ^= 1;
  }

  const int b = bh >> 4, hh = bh & 15;
  #pragma unroll
  for(int mf = 0; mf < 2; ++mf){
    l_part[mf] += __shfl_xor(l_part[mf], 16);
    l_part[mf] += __shfl_xor(l_part[mf], 32);
    float i0 = 1.0f / __shfl(l_part[mf], g * 4 + 0);
    float i1 = 1.0f / __shfl(l_part[mf], g * 4 + 1);
    float i2 = 1.0f / __shfl(l_part[mf], g * 4 + 2);
    float i3 = 1.0f / __shfl(l_part[mf], g * 4 + 3);
    #pragma unroll
    for(int nf = 0; nf < 4; ++nf){
      o[mf][nf][0] *= i0; o[mf][nf][1] *= i1; o[mf][nf][2] *= i2; o[mf][nf][3] *= i3;
      #pragma unroll
      for(int r = 0; r < 4; ++r){
        size_t row = (size_t)b * 1024 + q0 + mf * 16 + g * 4 + r;
        ow[row * 1024 + hh * 64 + nf * 16 + c0] = f2bf(o[mf][nf][r]);
      }
    }
  }
}

// ---- workspace layout (bytes) ----
//   bfT    @ 0         16,777,216   tensor bf16 (8192x1024)
//   bfWq   @ 16777216   6,291,456   w_qkv bf16 (3072x1024)
//   bfWp   @ 23068672   2,097,152   w_proj bf16 (1024x1024)
//   cs     @ 25165824     524,288   RoPE table float2 (1024x64)
//   qw     @ 25690112  16,777,216   Q rope'd*scale bf16 [bh][1024][64]
//   kw     @ 42467328  16,777,216   K rope'd bf16 [bh][1024][64]
//   vtw    @ 59244544  16,777,216   V^T bf16 [bh][64][1024]
//   ow     @ 76021760  16,777,216   attn out bf16 [b*n][c]

extern "C" void kernel_launch(void* const* d_in, const int* in_sizes, int n_in,
                              void* d_out, int out_size, void* d_ws, size_t ws_size,
                              hipStream_t stream){
  const float* tensor = (const float*)d_in[0];
  const float* w_qkv  = (const float*)d_in[1];
  const float* w_proj = (const float*)d_in[2];
  char* ws = (char*)d_ws;
  unsigned short* bfT  = (unsigned short*)(ws);
  unsigned short* bfWq = (unsigned short*)(ws + 16777216);
  unsigned short* bfWp = (unsigned short*)(ws + 23068672);
  float2*         cs   = (float2*)        (ws + 25165824);
  unsigned short* qw   = (unsigned short*)(ws + 25690112);
  unsigned short* kw   = (unsigned short*)(ws + 42467328);
  unsigned short* vtw  = (unsigned short*)(ws + 59244544);
  unsigned short* owp  = (unsigned short*)(ws + 76021760);

  cvt4<<<8192, 256, 0, stream>>>((const floatx4*)tensor, (ushortx4*)bfT, 2097152);
  cvt4<<<3072, 256, 0, stream>>>((const floatx4*)w_qkv,  (ushortx4*)bfWq, 786432);
  cvt4<<<1024, 256, 0, stream>>>((const floatx4*)w_proj, (ushortx4*)bfWp, 262144);
  cs_init<<<256, 256, 0, stream>>>(cs);

  // QKV: M=8192, N=3072, K=1024 ; fused RoPE epilogue (grid 32x12 = 384 blocks)
  gemm8<1><<<384, 512, 0, stream>>>(bfT, bfWq, 1024, 3072, 12,
                                    nullptr, cs, qw, kw, vtw);
  // attention: 512 blocks x 512 threads
  attn_kernel<<<512, 512, 0, stream>>>(qw, kw, vtw, owp);
  // proj: M=8192, N=1024, K=1024 ; f32 out (grid 32x4 = 128 blocks)
  gemm8<0><<<128, 512, 0, stream>>>(owp, bfWp, 1024, 1024, 4,
                                    (float*)d_out, nullptr, nullptr, nullptr, nullptr);
}

// Round 8
// 163.941 us; speedup vs baseline: 1.1452x; 1.0682x over previous
//
#include <hip/hip_runtime.h>

// ---- vector types (ext_vector for [] indexing; avoid HIP name collisions) ----
typedef __attribute__((ext_vector_type(8))) short short8v;      // 8 bf16 (4 VGPR) MFMA frag
typedef __attribute__((ext_vector_type(4))) float floatx4;      // MFMA accum
typedef __attribute__((ext_vector_type(4))) unsigned short ushortx4;

// RNE f32->bf16, 3 VALU ops (values are finite; no NaN path needed)
__device__ __forceinline__ unsigned short f2bf(float f){
  unsigned int u = __float_as_uint(f);
  u += 0x7fffu + ((u >> 16) & 1u);
  return (unsigned short)(u >> 16);
}

__device__ __forceinline__ void gload_lds16(const void* g, void* l){
  __builtin_amdgcn_global_load_lds((const __attribute__((address_space(1))) void*)g,
                                   (__attribute__((address_space(3))) void*)l, 16, 0, 0);
}

// ---- f32 -> bf16 convert, vectorized (G13) ----
__global__ __launch_bounds__(256) void cvt4(const floatx4* __restrict__ s,
                                            ushortx4* __restrict__ d, int n4){
  int i = blockIdx.x * 256 + threadIdx.x;
  if(i < n4){
    floatx4 v = s[i];
    ushortx4 o;
    #pragma unroll
    for(int j = 0; j < 4; ++j) o[j] = f2bf(v[j]);
    d[i] = o;
  }
}

// ---- 2D RoPE cos/sin table: cs[p*64+d] = (cos theta, sin theta) ----
__global__ __launch_bounds__(256) void cs_init(float2* __restrict__ cs){
  int i = blockIdx.x * 256 + threadIdx.x;     // 0..65535
  int p = i >> 6, d = i & 63;
  int y = p >> 5, x = p & 31;
  int dd = d & 31;
  float ifr = powf(10000.0f, -(float)dd * (1.0f / 32.0f));
  float th = (float)(d < 32 ? y : x) * ifr;
  cs[i].x = cosf(th);
  cs[i].y = sinf(th);
}

// ---- 8-phase BMx256 GEMM  C = A * B^T  (A: [M][K], B: [N][K], bf16) ----
// BK=64 (two K-halves of 32), 8 waves (2M x 4N), 512 thr. Raw s_barrier +
// counted vmcnt keeps stages in flight across barriers (T3+T4).
// BM=256: 4 MFMA clusters/tile, vmcnt(4); LDS 128KB; used when M-panels large.
// BM=128: 2 MFMA clusters/tile (16 MFMA each), vmcnt(3); LDS 96KB; halves
//         per-block work -> even rounds (QKV 768 = 3x256, proj 256 = 1x256).
// LDS chunk swizzle: chunk = g ^ ((row>>1)&3), inverse-applied on global src.
// EPI=0: f32 C. EPI=1: QKV epilogue (RoPE q/k, q*=0.125*log2e, V transposed).
template<int EPI, int BM>
__global__ __launch_bounds__(512, 2) void gemm8(
    const unsigned short* __restrict__ A,
    const unsigned short* __restrict__ B,
    int K, int N, int NXB,
    float* __restrict__ Cf,
    const float2* __restrict__ cs,
    unsigned short* __restrict__ qw,
    unsigned short* __restrict__ kw,
    unsigned short* __restrict__ vtw)
{
  constexpr int MF = BM / 32;           // acc rows (8 or 4)
  constexpr int WR = BM / 2;            // wave rows (128 or 64)
  constexpr int AKH = BM * 64;          // A bytes per kh-half (16K or 8K)
  __shared__ char lds[(BM + 256) * 256];  // A: 4*AKH, then B: 64K
  const int tid = threadIdx.x;
  const int w = tid >> 6, lane = tid & 63;
  const int g = lane >> 4, c0 = lane & 15;
  const int wm = w >> 2, wn = w & 3;    // 2 x 4 wave grid
  const int NT = K >> 6;                // K-tiles of 64

  // XCD-bijective block decode (nwg % 8 == 0)
  const int per = gridDim.x >> 3;
  const int wg = (blockIdx.x & 7) * per + (blockIdx.x >> 3);
  const int by = wg / NXB, bx = wg % NXB;
  const size_t m0 = (size_t)by * BM;
  const size_t n0 = (size_t)bx * 256;

  // staging: ci covers (row=ci>>2, chunk=ci&3) of a [rows][32] half.
  // LDS dest linear; global src chunk = (ci&3) ^ ((row>>1)&3)  [involution]
  const int row0 = tid >> 2;                       // 0..127
  const int xch = (tid & 3) ^ ((tid >> 3) & 3);
  const unsigned short* sA0 = A + (m0 + row0) * K + xch * 8;
  const unsigned short* sA1 = A + (m0 + row0 + 128) * K + xch * 8;   // BM=256 only
  const unsigned short* sB0 = B + (n0 + row0) * K + xch * 8;
  const unsigned short* sB1 = B + (n0 + row0 + 128) * K + xch * 8;
  char* const Ald = lds;
  char* const Bld = lds + 4 * AKH;
  const int wb = w * 1024;              // wave-uniform LDS dest base (lane*16 by HW)

  auto stA = [&](int t, int buf, int kh){
    char* d = Ald + buf * 2 * AKH + kh * AKH + wb;
    gload_lds16(sA0 + t * 64 + kh * 32, d);
    if constexpr (BM == 256) gload_lds16(sA1 + t * 64 + kh * 32, d + 8192);
  };
  auto stB = [&](int t, int buf, int kh){
    char* d = Bld + buf * 32768 + kh * 16384 + wb;
    gload_lds16(sB0 + t * 64 + kh * 32, d);
    gload_lds16(sB1 + t * 64 + kh * 32, d + 8192);
  };

  // swizzled read: chunk = g ^ ((row>>1)&3); row&3 = c0&3 for all frag rows
  const int archy = (g ^ ((c0 >> 1) & 3)) << 4;
  auto rdA = [&](int buf, int kh, int mf) -> short8v {
    return *(const short8v*)(Ald + buf * 2 * AKH + kh * AKH +
                             (wm * WR + mf * 16 + c0) * 64 + archy);
  };
  auto rdB = [&](int buf, int kh, int nf) -> short8v {
    return *(const short8v*)(Bld + buf * 32768 + kh * 16384 +
                             (wn * 64 + nf * 16 + c0) * 64 + archy);
  };

  floatx4 acc[MF][4] = {};

#define BARX() do{ __builtin_amdgcn_s_barrier(); __builtin_amdgcn_sched_barrier(0); }while(0)
#define VMC() do{ if constexpr (BM == 256) asm volatile("s_waitcnt vmcnt(4)" ::: "memory"); \
                  else                     asm volatile("s_waitcnt vmcnt(3)" ::: "memory"); }while(0)

  auto tile4 = [&](int t, int buf){
    const int ob = buf ^ 1;
    const int tn1 = (t + 1 < NT) ? t + 1 : NT - 1;
    const int tn2 = (t + 2 < NT) ? t + 2 : NT - 1;
    if constexpr (BM == 256){
      short8v am[4], bn[4];
      // ph1: kh0 B-all + A mf0-3 ; stage A,B(t+1) kh1 -> other buf
      #pragma unroll
      for(int nf = 0; nf < 4; ++nf) bn[nf] = rdB(buf, 0, nf);
      #pragma unroll
      for(int mf = 0; mf < 4; ++mf) am[mf] = rdA(buf, 0, mf);
      stA(tn1, ob, 1); stB(tn1, ob, 1);
      BARX();
      __builtin_amdgcn_s_setprio(1);
      #pragma unroll
      for(int mf = 0; mf < 4; ++mf)
        #pragma unroll
        for(int nf = 0; nf < 4; ++nf)
          acc[mf][nf] = __builtin_amdgcn_mfma_f32_16x16x32_bf16(am[mf], bn[nf], acc[mf][nf], 0, 0, 0);
      __builtin_amdgcn_s_setprio(0);
      BARX();
      // ph2: kh0 A mf4-7
      #pragma unroll
      for(int mf = 0; mf < 4; ++mf) am[mf] = rdA(buf, 0, 4 + mf);
      BARX();
      __builtin_amdgcn_s_setprio(1);
      #pragma unroll
      for(int mf = 0; mf < 4; ++mf)
        #pragma unroll
        for(int nf = 0; nf < 4; ++nf)
          acc[4 + mf][nf] = __builtin_amdgcn_mfma_f32_16x16x32_bf16(am[mf], bn[nf], acc[4 + mf][nf], 0, 0, 0);
      __builtin_amdgcn_s_setprio(0);
      BARX();
      // ph3: kh1 B-all + A mf0-3 ; stage A(t+2) kh0 -> this buf
      #pragma unroll
      for(int nf = 0; nf < 4; ++nf) bn[nf] = rdB(buf, 1, nf);
      #pragma unroll
      for(int mf = 0; mf < 4; ++mf) am[mf] = rdA(buf, 1, mf);
      stA(tn2, buf, 0);
      BARX();
      __builtin_amdgcn_s_setprio(1);
      #pragma unroll
      for(int mf = 0; mf < 4; ++mf)
        #pragma unroll
        for(int nf = 0; nf < 4; ++nf)
          acc[mf][nf] = __builtin_amdgcn_mfma_f32_16x16x32_bf16(am[mf], bn[nf], acc[mf][nf], 0, 0, 0);
      __builtin_amdgcn_s_setprio(0);
      BARX();
      // ph4: kh1 A mf4-7 ; stage B(t+2) kh0 ; counted vmcnt then barrier
      #pragma unroll
      for(int mf = 0; mf < 4; ++mf) am[mf] = rdA(buf, 1, 4 + mf);
      stB(tn2, buf, 0);
      BARX();
      __builtin_amdgcn_s_setprio(1);
      #pragma unroll
      for(int mf = 0; mf < 4; ++mf)
        #pragma unroll
        for(int nf = 0; nf < 4; ++nf)
          acc[4 + mf][nf] = __builtin_amdgcn_mfma_f32_16x16x32_bf16(am[mf], bn[nf], acc[4 + mf][nf], 0, 0, 0);
      __builtin_amdgcn_s_setprio(0);
      VMC();
      BARX();
    } else {
      // BM=128: 2 phases of 16 MFMA (kh0, kh1); 3 stage-loads per phase
      short8v am[4], bn[4];
      // phA: kh0 reads ; stage A,B(t+1) kh1 -> other buf
      #pragma unroll
      for(int nf = 0; nf < 4; ++nf) bn[nf] = rdB(buf, 0, nf);
      #pragma unroll
      for(int mf = 0; mf < 4; ++mf) am[mf] = rdA(buf, 0, mf);
      stA(tn1, ob, 1); stB(tn1, ob, 1);
      BARX();
      __builtin_amdgcn_s_setprio(1);
      #pragma unroll
      for(int mf = 0; mf < 4; ++mf)
        #pragma unroll
        for(int nf = 0; nf < 4; ++nf)
          acc[mf][nf] = __builtin_amdgcn_mfma_f32_16x16x32_bf16(am[mf], bn[nf], acc[mf][nf], 0, 0, 0);
      __builtin_amdgcn_s_setprio(0);
      BARX();
      // phB: kh1 reads ; stage A,B(t+2) kh0 -> this buf (kh0 reads done phA)
      #pragma unroll
      for(int nf = 0; nf < 4; ++nf) bn[nf] = rdB(buf, 1, nf);
      #pragma unroll
      for(int mf = 0; mf < 4; ++mf) am[mf] = rdA(buf, 1, mf);
      stA(tn2, buf, 0); stB(tn2, buf, 0);
      BARX();
      __builtin_amdgcn_s_setprio(1);
      #pragma unroll
      for(int mf = 0; mf < 4; ++mf)
        #pragma unroll
        for(int nf = 0; nf < 4; ++nf)
          acc[mf][nf] = __builtin_amdgcn_mfma_f32_16x16x32_bf16(am[mf], bn[nf], acc[mf][nf], 0, 0, 0);
      __builtin_amdgcn_s_setprio(0);
      VMC();
      BARX();
    }
  };

  // prologue: tile0 full + tile1 kh0; wait tile0 (leave tile1-kh0 flying)
  stA(0, 0, 0); stB(0, 0, 0);
  stA(0, 0, 1); stB(0, 0, 1);
  stA(1, 1, 0); stB(1, 1, 0);
  VMC();
  BARX();

  for(int t = 0; t < NT; t += 2){ tile4(t, 0); tile4(t + 1, 1); }
  __syncthreads();    // full drain: no dangling gload_lds writes past kernel end
#undef BARX
#undef VMC

  // ---- epilogue ---- C-layout: col = c0, row = g*4 + r  [m89-verified]
  if(EPI == 0){
    #pragma unroll
    for(int mf = 0; mf < MF; ++mf){
      size_t mrow = m0 + wm * WR + mf * 16 + g * 4;
      #pragma unroll
      for(int nf = 0; nf < 4; ++nf){
        size_t n = n0 + wn * 64 + nf * 16 + c0;
        #pragma unroll
        for(int r = 0; r < 4; ++r)
          Cf[(mrow + r) * N + n] = acc[mf][nf][r];
      }
    }
  } else {
    int t = (int)(n0 >> 6) + wn;          // 64-col group: 0..47
    int sect = t % 3, hh = t / 3;         // 0=q,1=k,2=v ; head
    if(sect == 2){
      // V -> V^T [bh][64][1024]
      #pragma unroll
      for(int mf = 0; mf < MF; ++mf){
        size_t m = m0 + wm * WR + mf * 16 + g * 4;
        int b = (int)(m >> 10); int p = (int)(m & 1023);
        #pragma unroll
        for(int nf = 0; nf < 4; ++nf){
          int d = nf * 16 + c0;
          ushortx4 pk;
          #pragma unroll
          for(int r = 0; r < 4; ++r) pk[r] = f2bf(acc[mf][nf][r]);
          *(ushortx4*)(vtw + ((size_t)(b * 16 + hh) * 64 + d) * 1024 + p) = pk;
        }
      }
    } else {
      // RoPE: pairs (d, d+32) live in frags (nf, nf+2) of the same thread
      unsigned short* dst = (sect == 0) ? qw : kw;
      const float qs = (sect == 0) ? 0.18033688011112042f : 1.0f;  // 0.125*log2e
      #pragma unroll
      for(int mf = 0; mf < MF; ++mf){
        #pragma unroll
        for(int r = 0; r < 4; ++r){
          size_t m = m0 + wm * WR + mf * 16 + g * 4 + r;
          int b = (int)(m >> 10); int p = (int)(m & 1023);
          const float2* csr = cs + (size_t)p * 64;
          unsigned short* orow = dst + ((size_t)(b * 16 + hh) * 1024 + p) * 64;
          #pragma unroll
          for(int nf = 0; nf < 2; ++nf){
            int d = nf * 16 + c0;
            float x1 = acc[mf][nf][r], x2 = acc[mf][nf + 2][r];
            float2 cc1 = csr[d], cc2 = csr[d + 32];
            orow[d]      = f2bf((x1 * cc1.x - x2 * cc1.y) * qs);
            orow[d + 32] = f2bf((x2 * cc2.x + x1 * cc2.y) * qs);
          }
        }
      }
    }
  }
}

// ---- flash attention v4b: 512 blocks x 512 thr (8 waves, 32 q-rows each) ----
// K/V tiles staged in LDS (shared by 8 waves), double-buffered, prefetched one
// iteration ahead via global_load_lds. XOR-swizzled K/V LDS layout.
// exp2-domain softmax, defer-max, deferred l-reduce, wave-private P buffer.
__global__ __launch_bounds__(512, 4) void attn_kernel(
    const unsigned short* __restrict__ qw,
    const unsigned short* __restrict__ kw,
    const unsigned short* __restrict__ vtw,
    unsigned short* __restrict__ ow)
{
  __shared__ char smem[65536];
  const int tid = threadIdx.x;
  const int w = tid >> 6, lane = tid & 63;
  const int g = lane >> 4, c0 = lane & 15;
  const int bb = blockIdx.x;                  // 0..511
  const int xcd = bb & 7, slot = bb >> 3;
  const int bh = xcd + ((slot >> 2) << 3);
  const int qt = slot & 3;
  const size_t bhoff = (size_t)bh * 1024 * 64;
  const unsigned short* Qb = qw + bhoff;
  const unsigned short* Kb = kw + bhoff;
  const unsigned short* Vb = vtw + bhoff;
  const int q0 = qt * 256 + w * 32;
  char* Pw = smem + 32768 + w * 4096;

  const int srow = tid >> 3;
  const int sjx = ((tid & 7) ^ (srow & 7)) << 3;
  const unsigned short* ksrc = Kb + srow * 64 + sjx;
  const unsigned short* vsrc = Vb + (size_t)srow * 1024 + sjx;
  const int wbase = w * 1024;

  short8v bq[2][2];
  #pragma unroll
  for(int qf = 0; qf < 2; ++qf)
    #pragma unroll
    for(int i = 0; i < 2; ++i)
      bq[qf][i] = *(const short8v*)(Qb + (size_t)(q0 + qf * 16 + c0) * 64 + g * 8 + i * 32);

  floatx4 o[2][4] = {};
  float m_run[2] = {-1e30f, -1e30f};
  float l_part[2] = {0.0f, 0.0f};

  gload_lds16(ksrc, smem + wbase);
  gload_lds16(vsrc, smem + 8192 + wbase);
  __syncthreads();

  int cur = 0;
  for(int kv0 = 0; kv0 < 1024; kv0 += 64){
    char* Ksm = smem + cur * 16384;
    char* Vsm = smem + cur * 16384 + 8192;
    if(kv0 + 64 < 1024){
      char* alt = smem + (cur ^ 1) * 16384;
      gload_lds16(ksrc + (size_t)(kv0 + 64) * 64, alt + wbase);
      gload_lds16(vsrc + kv0 + 64, alt + 8192 + wbase);
    }
    floatx4 st[4][2];
    #pragma unroll
    for(int kf = 0; kf < 4; ++kf){
      const int krow = kf * 16 + c0;
      const char* kr = Ksm + (krow << 7);
      short8v ka0 = *(const short8v*)(kr + (((g    ) ^ (c0 & 7)) << 4));
      short8v ka1 = *(const short8v*)(kr + (((g + 4) ^ (c0 & 7)) << 4));
      #pragma unroll
      for(int qf = 0; qf < 2; ++qf){
        floatx4 z = {};
        z = __builtin_amdgcn_mfma_f32_16x16x32_bf16(ka0, bq[qf][0], z, 0, 0, 0);
        st[kf][qf] = __builtin_amdgcn_mfma_f32_16x16x32_bf16(ka1, bq[qf][1], z, 0, 0, 0);
      }
    }
    float vmax[2];
    #pragma unroll
    for(int qf = 0; qf < 2; ++qf){
      float vm = -1e30f;
      #pragma unroll
      for(int kf = 0; kf < 4; ++kf)
        #pragma unroll
        for(int r = 0; r < 4; ++r) vm = fmaxf(vm, st[kf][qf][r]);
      vm = fmaxf(vm, __shfl_xor(vm, 16));
      vm = fmaxf(vm, __shfl_xor(vm, 32));
      vmax[qf] = vm;
    }
    if(!__all(vmax[0] <= m_run[0] + 8.0f && vmax[1] <= m_run[1] + 8.0f)){
      #pragma unroll
      for(int qf = 0; qf < 2; ++qf){
        float m_new = fmaxf(m_run[qf], vmax[qf]);
        float sc = __builtin_amdgcn_exp2f(m_run[qf] - m_new);
        l_part[qf] *= sc;
        m_run[qf] = m_new;
        float f0 = __shfl(sc, g * 4 + 0);
        float f1 = __shfl(sc, g * 4 + 1);
        float f2 = __shfl(sc, g * 4 + 2);
        float f3 = __shfl(sc, g * 4 + 3);
        #pragma unroll
        for(int nf = 0; nf < 4; ++nf){
          o[qf][nf][0] *= f0; o[qf][nf][1] *= f1; o[qf][nf][2] *= f2; o[qf][nf][3] *= f3;
        }
      }
    }
    #pragma unroll
    for(int qf = 0; qf < 2; ++qf){
      float ps = 0.0f;
      #pragma unroll
      for(int kf = 0; kf < 4; ++kf){
        ushortx4 pk;
        #pragma unroll
        for(int r = 0; r < 4; ++r){
          float e = __builtin_amdgcn_exp2f(st[kf][qf][r] - m_run[qf]);
          ps += e;
          pk[r] = f2bf(e);
        }
        int byo = (qf << 11) + (c0 << 7) + (kf << 5) + (g << 3);
        byo ^= (c0 & 7) << 4;
        *(ushortx4*)(Pw + byo) = pk;
      }
      l_part[qf] += ps;
    }
    short8v pa[2][2];
    #pragma unroll
    for(int mf = 0; mf < 2; ++mf)
      #pragma unroll
      for(int i = 0; i < 2; ++i){
        int byo = (mf << 11) + (c0 << 7) + (i << 6) + (g << 4);
        byo ^= (c0 & 7) << 4;
        pa[mf][i] = *(const short8v*)(Pw + byo);
      }
    #pragma unroll
    for(int nf = 0; nf < 4; ++nf){
      const int vrow = nf * 16 + c0;
      const char* vr = Vsm + (vrow << 7);
      short8v v0 = *(const short8v*)(vr + (((g    ) ^ (c0 & 7)) << 4));
      short8v v1 = *(const short8v*)(vr + (((g + 4) ^ (c0 & 7)) << 4));
      #pragma unroll
      for(int mf = 0; mf < 2; ++mf){
        o[mf][nf] = __builtin_amdgcn_mfma_f32_16x16x32_bf16(pa[mf][0], v0, o[mf][nf], 0, 0, 0);
        o[mf][nf] = __builtin_amdgcn_mfma_f32_16x16x32_bf16(pa[mf][1], v1, o[mf][nf], 0, 0, 0);
      }
    }
    __syncthreads();
    cur ^= 1;
  }

  const int b = bh >> 4, hh = bh & 15;
  #pragma unroll
  for(int mf = 0; mf < 2; ++mf){
    l_part[mf] += __shfl_xor(l_part[mf], 16);
    l_part[mf] += __shfl_xor(l_part[mf], 32);
    float i0 = 1.0f / __shfl(l_part[mf], g * 4 + 0);
    float i1 = 1.0f / __shfl(l_part[mf], g * 4 + 1);
    float i2 = 1.0f / __shfl(l_part[mf], g * 4 + 2);
    float i3 = 1.0f / __shfl(l_part[mf], g * 4 + 3);
    #pragma unroll
    for(int nf = 0; nf < 4; ++nf){
      o[mf][nf][0] *= i0; o[mf][nf][1] *= i1; o[mf][nf][2] *= i2; o[mf][nf][3] *= i3;
      #pragma unroll
      for(int r = 0; r < 4; ++r){
        size_t row = (size_t)b * 1024 + q0 + mf * 16 + g * 4 + r;
        ow[row * 1024 + hh * 64 + nf * 16 + c0] = f2bf(o[mf][nf][r]);
      }
    }
  }
}

// ---- workspace layout (bytes) ----
//   bfT    @ 0         16,777,216   tensor bf16 (8192x1024)
//   bfWq   @ 16777216   6,291,456   w_qkv bf16 (3072x1024)
//   bfWp   @ 23068672   2,097,152   w_proj bf16 (1024x1024)
//   cs     @ 25165824     524,288   RoPE table float2 (1024x64)
//   qw     @ 25690112  16,777,216   Q rope'd*scale bf16 [bh][1024][64]
//   kw     @ 42467328  16,777,216   K rope'd bf16 [bh][1024][64]
//   vtw    @ 59244544  16,777,216   V^T bf16 [bh][64][1024]
//   ow     @ 76021760  16,777,216   attn out bf16 [b*n][c]

extern "C" void kernel_launch(void* const* d_in, const int* in_sizes, int n_in,
                              void* d_out, int out_size, void* d_ws, size_t ws_size,
                              hipStream_t stream){
  const float* tensor = (const float*)d_in[0];
  const float* w_qkv  = (const float*)d_in[1];
  const float* w_proj = (const float*)d_in[2];
  char* ws = (char*)d_ws;
  unsigned short* bfT  = (unsigned short*)(ws);
  unsigned short* bfWq = (unsigned short*)(ws + 16777216);
  unsigned short* bfWp = (unsigned short*)(ws + 23068672);
  float2*         cs   = (float2*)        (ws + 25165824);
  unsigned short* qw   = (unsigned short*)(ws + 25690112);
  unsigned short* kw   = (unsigned short*)(ws + 42467328);
  unsigned short* vtw  = (unsigned short*)(ws + 59244544);
  unsigned short* owp  = (unsigned short*)(ws + 76021760);

  cvt4<<<8192, 256, 0, stream>>>((const floatx4*)tensor, (ushortx4*)bfT, 2097152);
  cvt4<<<3072, 256, 0, stream>>>((const floatx4*)w_qkv,  (ushortx4*)bfWq, 786432);
  cvt4<<<1024, 256, 0, stream>>>((const floatx4*)w_proj, (ushortx4*)bfWp, 262144);
  cs_init<<<256, 256, 0, stream>>>(cs);

  // QKV: M=8192, N=3072, K=1024 ; BM=128 -> grid 64x12 = 768 = 3 even rounds
  gemm8<1, 128><<<768, 512, 0, stream>>>(bfT, bfWq, 1024, 3072, 12,
                                         nullptr, cs, qw, kw, vtw);
  // attention: 512 blocks x 512 threads
  attn_kernel<<<512, 512, 0, stream>>>(qw, kw, vtw, owp);
  // proj: M=8192, N=1024, K=1024 ; BM=128 -> grid 64x4 = 256 = 1 even round
  gemm8<0, 128><<<256, 512, 0, stream>>>(owp, bfWp, 1024, 1024, 4,
                                         (float*)d_out, nullptr, nullptr, nullptr, nullptr);
}

// Round 9
// 160.872 us; speedup vs baseline: 1.1670x; 1.0191x over previous
//
#include <hip/hip_runtime.h>

// ---- vector types (ext_vector for [] indexing; avoid HIP name collisions) ----
typedef __attribute__((ext_vector_type(8))) short short8v;      // 8 bf16 (4 VGPR) MFMA frag
typedef __attribute__((ext_vector_type(4))) float floatx4;      // MFMA accum
typedef __attribute__((ext_vector_type(4))) unsigned short ushortx4;

// RNE f32->bf16, 3 VALU ops (values are finite; no NaN path needed)
__device__ __forceinline__ unsigned int f2bf(float f){
  unsigned int u = __float_as_uint(f);
  u += 0x7fffu + ((u >> 16) & 1u);
  return u >> 16;
}

__device__ __forceinline__ void gload_lds16(const void* g, void* l){
  __builtin_amdgcn_global_load_lds((const __attribute__((address_space(1))) void*)g,
                                   (__attribute__((address_space(3))) void*)l, 16, 0, 0);
}

// ---- fused prep: f32->bf16 for tensor/w_qkv/w_proj + RoPE cos/sin table ----
// region boundaries are multiples of 256 -> each block is branch-uniform.
__global__ __launch_bounds__(256) void prep(
    const floatx4* __restrict__ t,  ushortx4* __restrict__ dt,
    const floatx4* __restrict__ wq, ushortx4* __restrict__ dq,
    const floatx4* __restrict__ wp, ushortx4* __restrict__ dp,
    float2* __restrict__ cs)
{
  int i = blockIdx.x * 256 + threadIdx.x;
  if(i < 3145728){
    const floatx4* s; ushortx4* d; int j;
    if(i < 2097152){ s = t;  d = dt; j = i; }
    else if(i < 2883584){ s = wq; d = dq; j = i - 2097152; }
    else { s = wp; d = dp; j = i - 2883584; }
    floatx4 v = s[j];
    ushortx4 o;
    #pragma unroll
    for(int k = 0; k < 4; ++k) o[k] = (unsigned short)f2bf(v[k]);
    d[j] = o;
  } else {
    int j = i - 3145728;              // 0..65535
    int p = j >> 6, dd = j & 63;
    int y = p >> 5, x = p & 31;
    int dm = dd & 31;
    float ifr = powf(10000.0f, -(float)dm * (1.0f / 32.0f));
    float th = (float)(dd < 32 ? y : x) * ifr;
    cs[j].x = cosf(th);
    cs[j].y = sinf(th);
  }
}

// ---- 8-phase BMx256 GEMM  C = A * B^T  (A: [M][K], B: [N][K], bf16) ----
// BK=64 (two K-halves of 32), 8 waves (2M x 4N), 512 thr. Raw s_barrier +
// counted vmcnt keeps stages in flight across barriers (T3+T4).
// BM=128: 2 MFMA clusters/tile (16 MFMA each); per-phase vmcnt(6) placed
//   AFTER the MFMA cluster -> each staged group gets ~2 phases to land.
// LDS chunk swizzle: chunk = g ^ ((row>>1)&3), inverse-applied on global src.
// EPI=0: f32 C. EPI=1: QKV epilogue (RoPE q/k, q*=0.125*log2e, V transposed).
template<int EPI, int BM>
__global__ __launch_bounds__(512, 2) void gemm8(
    const unsigned short* __restrict__ A,
    const unsigned short* __restrict__ B,
    int K, int N, int NXB,
    float* __restrict__ Cf,
    const float2* __restrict__ cs,
    unsigned short* __restrict__ qw,
    unsigned short* __restrict__ kw,
    unsigned short* __restrict__ vtw)
{
  constexpr int MF = BM / 32;           // acc rows (4 for BM=128)
  constexpr int WR = BM / 2;            // wave rows (64)
  constexpr int AKH = BM * 64;          // A bytes per kh-half (8K)
  __shared__ char lds[(BM + 256) * 256];  // A: 4*AKH, then B: 64K
  const int tid = threadIdx.x;
  const int w = tid >> 6, lane = tid & 63;
  const int g = lane >> 4, c0 = lane & 15;
  const int wm = w >> 2, wn = w & 3;    // 2 x 4 wave grid
  const int NT = K >> 6;                // K-tiles of 64

  // XCD-bijective block decode (nwg % 8 == 0)
  const int per = gridDim.x >> 3;
  const int wg = (blockIdx.x & 7) * per + (blockIdx.x >> 3);
  const int by = wg / NXB, bx = wg % NXB;
  const size_t m0 = (size_t)by * BM;
  const size_t n0 = (size_t)bx * 256;

  // staging: ci covers (row=ci>>2, chunk=ci&3) of a [rows][32] half.
  // LDS dest linear; global src chunk = (ci&3) ^ ((row>>1)&3)  [involution]
  const int row0 = tid >> 2;                       // 0..127
  const int xch = (tid & 3) ^ ((tid >> 3) & 3);
  const unsigned short* sA0 = A + (m0 + row0) * K + xch * 8;
  const unsigned short* sB0 = B + (n0 + row0) * K + xch * 8;
  const unsigned short* sB1 = B + (n0 + row0 + 128) * K + xch * 8;
  char* const Ald = lds;
  char* const Bld = lds + 4 * AKH;
  const int wb = w * 1024;              // wave-uniform LDS dest base (lane*16 by HW)

  auto stA = [&](int t, int buf, int kh){
    char* d = Ald + buf * 2 * AKH + kh * AKH + wb;
    gload_lds16(sA0 + t * 64 + kh * 32, d);
  };
  auto stB = [&](int t, int buf, int kh){
    char* d = Bld + buf * 32768 + kh * 16384 + wb;
    gload_lds16(sB0 + t * 64 + kh * 32, d);
    gload_lds16(sB1 + t * 64 + kh * 32, d + 8192);
  };

  // swizzled read: chunk = g ^ ((row>>1)&3); row&3 = c0&3 for all frag rows
  const int archy = (g ^ ((c0 >> 1) & 3)) << 4;
  auto rdA = [&](int buf, int kh, int mf) -> short8v {
    return *(const short8v*)(Ald + buf * 2 * AKH + kh * AKH +
                             (wm * WR + mf * 16 + c0) * 64 + archy);
  };
  auto rdB = [&](int buf, int kh, int nf) -> short8v {
    return *(const short8v*)(Bld + buf * 32768 + kh * 16384 +
                             (wn * 64 + nf * 16 + c0) * 64 + archy);
  };

  floatx4 acc[MF][4] = {};

#define BARX() do{ __builtin_amdgcn_s_barrier(); __builtin_amdgcn_sched_barrier(0); }while(0)
#define VMC6() asm volatile("s_waitcnt vmcnt(6)" ::: "memory")

  auto tile2 = [&](int t, int buf){
    const int ob = buf ^ 1;
    const int tn1 = (t + 1 < NT) ? t + 1 : NT - 1;
    const int tn2 = (t + 2 < NT) ? t + 2 : NT - 1;
    short8v am[4], bn[4];
    // phA: kh0 reads ; stage A,B(t+1) kh1 -> other buf
    #pragma unroll
    for(int nf = 0; nf < 4; ++nf) bn[nf] = rdB(buf, 0, nf);
    #pragma unroll
    for(int mf = 0; mf < 4; ++mf) am[mf] = rdA(buf, 0, mf);
    stA(tn1, ob, 1); stB(tn1, ob, 1);
    BARX();
    __builtin_amdgcn_s_setprio(1);
    #pragma unroll
    for(int mf = 0; mf < 4; ++mf)
      #pragma unroll
      for(int nf = 0; nf < 4; ++nf)
        acc[mf][nf] = __builtin_amdgcn_mfma_f32_16x16x32_bf16(am[mf], bn[nf], acc[mf][nf], 0, 0, 0);
    __builtin_amdgcn_s_setprio(0);
    VMC6();              // covers t kh1 (issued 2 phases ago), read after next BARX
    BARX();
    // phB: kh1 reads ; stage A,B(t+2) kh0 -> this buf (kh0 reads done phA)
    #pragma unroll
    for(int nf = 0; nf < 4; ++nf) bn[nf] = rdB(buf, 1, nf);
    #pragma unroll
    for(int mf = 0; mf < 4; ++mf) am[mf] = rdA(buf, 1, mf);
    stA(tn2, buf, 0); stB(tn2, buf, 0);
    BARX();
    __builtin_amdgcn_s_setprio(1);
    #pragma unroll
    for(int mf = 0; mf < 4; ++mf)
      #pragma unroll
      for(int nf = 0; nf < 4; ++nf)
        acc[mf][nf] = __builtin_amdgcn_mfma_f32_16x16x32_bf16(am[mf], bn[nf], acc[mf][nf], 0, 0, 0);
    __builtin_amdgcn_s_setprio(0);
    VMC6();              // covers t+1 kh0 (issued 2 phases ago)
    BARX();
  };

  // prologue: tile0 full + tile1 kh0 (9 loads); allow 6 -> tile0 resident
  stA(0, 0, 0); stB(0, 0, 0);
  stA(0, 0, 1); stB(0, 0, 1);
  stA(1, 1, 0); stB(1, 1, 0);
  VMC6();
  BARX();

  for(int t = 0; t < NT; t += 2){ tile2(t, 0); tile2(t + 1, 1); }
  __syncthreads();    // full drain: no dangling gload_lds writes past kernel end
#undef BARX
#undef VMC6

  // ---- epilogue ---- C-layout: col = c0, row = g*4 + r  [m89-verified]
  if(EPI == 0){
    #pragma unroll
    for(int mf = 0; mf < MF; ++mf){
      size_t mrow = m0 + wm * WR + mf * 16 + g * 4;
      #pragma unroll
      for(int nf = 0; nf < 4; ++nf){
        size_t n = n0 + wn * 64 + nf * 16 + c0;
        #pragma unroll
        for(int r = 0; r < 4; ++r)
          Cf[(mrow + r) * N + n] = acc[mf][nf][r];
      }
    }
  } else {
    int t = (int)(n0 >> 6) + wn;          // 64-col group: 0..47
    int sect = t % 3, hh = t / 3;         // 0=q,1=k,2=v ; head
    if(sect == 2){
      // V -> V^T [bh][64][1024]
      #pragma unroll
      for(int mf = 0; mf < MF; ++mf){
        size_t m = m0 + wm * WR + mf * 16 + g * 4;
        int b = (int)(m >> 10); int p = (int)(m & 1023);
        #pragma unroll
        for(int nf = 0; nf < 4; ++nf){
          int d = nf * 16 + c0;
          ushortx4 pk;
          #pragma unroll
          for(int r = 0; r < 4; ++r) pk[r] = (unsigned short)f2bf(acc[mf][nf][r]);
          *(ushortx4*)(vtw + ((size_t)(b * 16 + hh) * 64 + d) * 1024 + p) = pk;
        }
      }
    } else {
      // RoPE: pairs (d, d+32) live in frags (nf, nf+2) of the same thread.
      // Pair-packed dword stores: even lane stores (d,d+1), odd stores (d+31,d+32).
      unsigned short* dst = (sect == 0) ? qw : kw;
      const float qs = (sect == 0) ? 0.18033688011112042f : 1.0f;  // 0.125*log2e
      const int codd = c0 & 1;
      #pragma unroll
      for(int mf = 0; mf < MF; ++mf){
        #pragma unroll
        for(int r = 0; r < 4; ++r){
          size_t m = m0 + wm * WR + mf * 16 + g * 4 + r;
          int b = (int)(m >> 10); int p = (int)(m & 1023);
          const float2* csr = cs + (size_t)p * 64;
          unsigned short* orow = dst + ((size_t)(b * 16 + hh) * 1024 + p) * 64;
          #pragma unroll
          for(int nf = 0; nf < 2; ++nf){
            int d = nf * 16 + c0;
            float x1 = acc[mf][nf][r], x2 = acc[mf][nf + 2][r];
            float2 cc1 = csr[d], cc2 = csr[d + 32];
            unsigned int u1 = f2bf((x1 * cc1.x - x2 * cc1.y) * qs);  // elem d
            unsigned int u2 = f2bf((x2 * cc2.x + x1 * cc2.y) * qs);  // elem d+32
            unsigned int p1 = (unsigned int)__shfl_xor((int)u1, 1);
            unsigned int p2 = (unsigned int)__shfl_xor((int)u2, 1);
            unsigned int val = codd ? (p2 | (u2 << 16)) : (u1 | (p1 << 16));
            int off = codd ? (d + 31) : d;
            *(unsigned int*)(orow + off) = val;
          }
        }
      }
    }
  }
}

// ---- flash attention v4b: 512 blocks x 512 thr (8 waves, 32 q-rows each) ----
// K/V tiles staged in LDS (shared by 8 waves), double-buffered, prefetched one
// iteration ahead via global_load_lds. XOR-swizzled K/V LDS layout.
// exp2-domain softmax, defer-max, deferred l-reduce, wave-private P buffer.
__global__ __launch_bounds__(512, 4) void attn_kernel(
    const unsigned short* __restrict__ qw,
    const unsigned short* __restrict__ kw,
    const unsigned short* __restrict__ vtw,
    unsigned short* __restrict__ ow)
{
  __shared__ char smem[65536];
  const int tid = threadIdx.x;
  const int w = tid >> 6, lane = tid & 63;
  const int g = lane >> 4, c0 = lane & 15;
  const int bb = blockIdx.x;                  // 0..511
  const int xcd = bb & 7, slot = bb >> 3;
  const int bh = xcd + ((slot >> 2) << 3);
  const int qt = slot & 3;
  const size_t bhoff = (size_t)bh * 1024 * 64;
  const unsigned short* Qb = qw + bhoff;
  const unsigned short* Kb = kw + bhoff;
  const unsigned short* Vb = vtw + bhoff;
  const int q0 = qt * 256 + w * 32;
  char* Pw = smem + 32768 + w * 4096;

  const int srow = tid >> 3;
  const int sjx = ((tid & 7) ^ (srow & 7)) << 3;
  const unsigned short* ksrc = Kb + srow * 64 + sjx;
  const unsigned short* vsrc = Vb + (size_t)srow * 1024 + sjx;
  const int wbase = w * 1024;

  short8v bq[2][2];
  #pragma unroll
  for(int qf = 0; qf < 2; ++qf)
    #pragma unroll
    for(int i = 0; i < 2; ++i)
      bq[qf][i] = *(const short8v*)(Qb + (size_t)(q0 + qf * 16 + c0) * 64 + g * 8 + i * 32);

  floatx4 o[2][4] = {};
  float m_run[2] = {-1e30f, -1e30f};
  float l_part[2] = {0.0f, 0.0f};

  gload_lds16(ksrc, smem + wbase);
  gload_lds16(vsrc, smem + 8192 + wbase);
  __syncthreads();

  int cur = 0;
  for(int kv0 = 0; kv0 < 1024; kv0 += 64){
    char* Ksm = smem + cur * 16384;
    char* Vsm = smem + cur * 16384 + 8192;
    if(kv0 + 64 < 1024){
      char* alt = smem + (cur ^ 1) * 16384;
      gload_lds16(ksrc + (size_t)(kv0 + 64) * 64, alt + wbase);
      gload_lds16(vsrc + kv0 + 64, alt + 8192 + wbase);
    }
    floatx4 st[4][2];
    #pragma unroll
    for(int kf = 0; kf < 4; ++kf){
      const int krow = kf * 16 + c0;
      const char* kr = Ksm + (krow << 7);
      short8v ka0 = *(const short8v*)(kr + (((g    ) ^ (c0 & 7)) << 4));
      short8v ka1 = *(const short8v*)(kr + (((g + 4) ^ (c0 & 7)) << 4));
      #pragma unroll
      for(int qf = 0; qf < 2; ++qf){
        floatx4 z = {};
        z = __builtin_amdgcn_mfma_f32_16x16x32_bf16(ka0, bq[qf][0], z, 0, 0, 0);
        st[kf][qf] = __builtin_amdgcn_mfma_f32_16x16x32_bf16(ka1, bq[qf][1], z, 0, 0, 0);
      }
    }
    float vmax[2];
    #pragma unroll
    for(int qf = 0; qf < 2; ++qf){
      float vm = -1e30f;
      #pragma unroll
      for(int kf = 0; kf < 4; ++kf)
        #pragma unroll
        for(int r = 0; r < 4; ++r) vm = fmaxf(vm, st[kf][qf][r]);
      vm = fmaxf(vm, __shfl_xor(vm, 16));
      vm = fmaxf(vm, __shfl_xor(vm, 32));
      vmax[qf] = vm;
    }
    if(!__all(vmax[0] <= m_run[0] + 8.0f && vmax[1] <= m_run[1] + 8.0f)){
      #pragma unroll
      for(int qf = 0; qf < 2; ++qf){
        float m_new = fmaxf(m_run[qf], vmax[qf]);
        float sc = __builtin_amdgcn_exp2f(m_run[qf] - m_new);
        l_part[qf] *= sc;
        m_run[qf] = m_new;
        float f0 = __shfl(sc, g * 4 + 0);
        float f1 = __shfl(sc, g * 4 + 1);
        float f2 = __shfl(sc, g * 4 + 2);
        float f3 = __shfl(sc, g * 4 + 3);
        #pragma unroll
        for(int nf = 0; nf < 4; ++nf){
          o[qf][nf][0] *= f0; o[qf][nf][1] *= f1; o[qf][nf][2] *= f2; o[qf][nf][3] *= f3;
        }
      }
    }
    #pragma unroll
    for(int qf = 0; qf < 2; ++qf){
      float ps = 0.0f;
      #pragma unroll
      for(int kf = 0; kf < 4; ++kf){
        ushortx4 pk;
        #pragma unroll
        for(int r = 0; r < 4; ++r){
          float e = __builtin_amdgcn_exp2f(st[kf][qf][r] - m_run[qf]);
          ps += e;
          pk[r] = (unsigned short)f2bf(e);
        }
        int byo = (qf << 11) + (c0 << 7) + (kf << 5) + (g << 3);
        byo ^= (c0 & 7) << 4;
        *(ushortx4*)(Pw + byo) = pk;
      }
      l_part[qf] += ps;
    }
    short8v pa[2][2];
    #pragma unroll
    for(int mf = 0; mf < 2; ++mf)
      #pragma unroll
      for(int i = 0; i < 2; ++i){
        int byo = (mf << 11) + (c0 << 7) + (i << 6) + (g << 4);
        byo ^= (c0 & 7) << 4;
        pa[mf][i] = *(const short8v*)(Pw + byo);
      }
    #pragma unroll
    for(int nf = 0; nf < 4; ++nf){
      const int vrow = nf * 16 + c0;
      const char* vr = Vsm + (vrow << 7);
      short8v v0 = *(const short8v*)(vr + (((g    ) ^ (c0 & 7)) << 4));
      short8v v1 = *(const short8v*)(vr + (((g + 4) ^ (c0 & 7)) << 4));
      #pragma unroll
      for(int mf = 0; mf < 2; ++mf){
        o[mf][nf] = __builtin_amdgcn_mfma_f32_16x16x32_bf16(pa[mf][0], v0, o[mf][nf], 0, 0, 0);
        o[mf][nf] = __builtin_amdgcn_mfma_f32_16x16x32_bf16(pa[mf][1], v1, o[mf][nf], 0, 0, 0);
      }
    }
    __syncthreads();
    cur ^= 1;
  }

  const int b = bh >> 4, hh = bh & 15;
  #pragma unroll
  for(int mf = 0; mf < 2; ++mf){
    l_part[mf] += __shfl_xor(l_part[mf], 16);
    l_part[mf] += __shfl_xor(l_part[mf], 32);
    float i0 = 1.0f / __shfl(l_part[mf], g * 4 + 0);
    float i1 = 1.0f / __shfl(l_part[mf], g * 4 + 1);
    float i2 = 1.0f / __shfl(l_part[mf], g * 4 + 2);
    float i3 = 1.0f / __shfl(l_part[mf], g * 4 + 3);
    #pragma unroll
    for(int nf = 0; nf < 4; ++nf){
      o[mf][nf][0] *= i0; o[mf][nf][1] *= i1; o[mf][nf][2] *= i2; o[mf][nf][3] *= i3;
      #pragma unroll
      for(int r = 0; r < 4; ++r){
        size_t row = (size_t)b * 1024 + q0 + mf * 16 + g * 4 + r;
        ow[row * 1024 + hh * 64 + nf * 16 + c0] = (unsigned short)f2bf(o[mf][nf][r]);
      }
    }
  }
}

// ---- workspace layout (bytes) ----
//   bfT    @ 0         16,777,216   tensor bf16 (8192x1024)
//   bfWq   @ 16777216   6,291,456   w_qkv bf16 (3072x1024)
//   bfWp   @ 23068672   2,097,152   w_proj bf16 (1024x1024)
//   cs     @ 25165824     524,288   RoPE table float2 (1024x64)
//   qw     @ 25690112  16,777,216   Q rope'd*scale bf16 [bh][1024][64]
//   kw     @ 42467328  16,777,216   K rope'd bf16 [bh][1024][64]
//   vtw    @ 59244544  16,777,216   V^T bf16 [bh][64][1024]
//   ow     @ 76021760  16,777,216   attn out bf16 [b*n][c]

extern "C" void kernel_launch(void* const* d_in, const int* in_sizes, int n_in,
                              void* d_out, int out_size, void* d_ws, size_t ws_size,
                              hipStream_t stream){
  const float* tensor = (const float*)d_in[0];
  const float* w_qkv  = (const float*)d_in[1];
  const float* w_proj = (const float*)d_in[2];
  char* ws = (char*)d_ws;
  unsigned short* bfT  = (unsigned short*)(ws);
  unsigned short* bfWq = (unsigned short*)(ws + 16777216);
  unsigned short* bfWp = (unsigned short*)(ws + 23068672);
  float2*         cs   = (float2*)        (ws + 25165824);
  unsigned short* qw   = (unsigned short*)(ws + 25690112);
  unsigned short* kw   = (unsigned short*)(ws + 42467328);
  unsigned short* vtw  = (unsigned short*)(ws + 59244544);
  unsigned short* owp  = (unsigned short*)(ws + 76021760);

  // fused convert + RoPE table: 3145728 cvt threads + 65536 cs threads
  prep<<<12544, 256, 0, stream>>>((const floatx4*)tensor, (ushortx4*)bfT,
                                  (const floatx4*)w_qkv,  (ushortx4*)bfWq,
                                  (const floatx4*)w_proj, (ushortx4*)bfWp, cs);

  // QKV: M=8192, N=3072, K=1024 ; BM=128 -> grid 64x12 = 768 = 3 even rounds
  gemm8<1, 128><<<768, 512, 0, stream>>>(bfT, bfWq, 1024, 3072, 12,
                                         nullptr, cs, qw, kw, vtw);
  // attention: 512 blocks x 512 threads
  attn_kernel<<<512, 512, 0, stream>>>(qw, kw, vtw, owp);
  // proj: M=8192, N=1024, K=1024 ; BM=128 -> grid 64x4 = 256 = 1 even round
  gemm8<0, 128><<<256, 512, 0, stream>>>(owp, bfWp, 1024, 1024, 4,
                                         (float*)d_out, nullptr, nullptr, nullptr, nullptr);
}